// Round 6
// baseline (337.939 us; speedup 1.0000x reference)
//
#include <hip/hip_runtime.h>

#define N 8192
#define FI 256
#define FO 128

typedef short bf16x8 __attribute__((ext_vector_type(8)));
typedef float f32x4 __attribute__((ext_vector_type(4)));
typedef unsigned long long u64;
typedef u64 u64x2 __attribute__((ext_vector_type(2)));

static __device__ __forceinline__ unsigned short f2bf(float x) {
  unsigned int u = __builtin_bit_cast(unsigned int, x);
  u = (u + 0x7fffu + ((u >> 16) & 1u)) >> 16;
  return (unsigned short)u;
}
static __device__ __forceinline__ float lrelu(float x) {
  return fmaxf(x, 0.01f * x);
}

// Kernel A: h = x@W (f32 accum); write h transposed bf16 h_t[FO][N]; ha1 = h@a1, ha2 = h@a2.
__global__ __launch_bounds__(256) void k_prep(
    const float* __restrict__ x, const float* __restrict__ W, const float* __restrict__ a,
    unsigned short* __restrict__ h_t, float* __restrict__ ha1, float* __restrict__ ha2) {
  __shared__ float xs[16][256];
  __shared__ float redA[16][2], redB[16][2];
  const int t = threadIdx.x;
  const int i0 = blockIdx.x * 16;
  #pragma unroll
  for (int ii = 0; ii < 16; ++ii)
    xs[ii][t & 255] = x[(long long)(i0 + ii) * FI + t];
  __syncthreads();
  const int rg = t >> 7;
  const int f = t & 127;
  float accs[8] = {0.f, 0.f, 0.f, 0.f, 0.f, 0.f, 0.f, 0.f};
  for (int k = 0; k < 256; ++k) {
    const float wv = W[k * FO + f];
    #pragma unroll
    for (int rr = 0; rr < 8; ++rr) accs[rr] = fmaf(xs[rg * 8 + rr][k], wv, accs[rr]);
  }
  {
    ushort4 s0, s1;
    s0.x = f2bf(accs[0]); s0.y = f2bf(accs[1]); s0.z = f2bf(accs[2]); s0.w = f2bf(accs[3]);
    s1.x = f2bf(accs[4]); s1.y = f2bf(accs[5]); s1.z = f2bf(accs[6]); s1.w = f2bf(accs[7]);
    unsigned short* dst = h_t + (long long)f * N + i0 + rg * 8;
    *(ushort4*)dst = s0;
    *(ushort4*)(dst + 4) = s1;
  }
  const float a1f = a[f];
  const float a2f = a[FO + f];
  const int lane = t & 63;
  const int wig = (t >> 6) & 1;
  #pragma unroll
  for (int rr = 0; rr < 8; ++rr) {
    float v1 = accs[rr] * a1f;
    float v2 = accs[rr] * a2f;
    #pragma unroll
    for (int off = 32; off; off >>= 1) { v1 += __shfl_xor(v1, off); v2 += __shfl_xor(v2, off); }
    if (lane == 0) { redA[rg * 8 + rr][wig] = v1; redB[rg * 8 + rr][wig] = v2; }
  }
  __syncthreads();
  if (t < 16) {
    ha1[i0 + t] = redA[t][0] + redA[t][1];
    ha2[i0 + t] = redB[t][0] + redB[t][1];
  }
}

// Kernel B: one wave per row. Stream adj once: ballot -> bitmask (ws) + online-softmax
// (m, s) over masked e = lrelu(ei + ha2[j]). Writes lse = m + log(s).
// Mask layout (ballot-interleaved): bit l of word mrow[it*4 + k] <-> j = it*256 + 4*l + k.
template <int WM>
__global__ __launch_bounds__(256) void k_mask(
    const int* __restrict__ adj, const float* __restrict__ ha1g, const float* __restrict__ ha2g,
    u64* __restrict__ msk, float* __restrict__ lse_row) {
  const int t = threadIdx.x;
  const int lane = t & 63;
  const int row = blockIdx.x * 4 + (t >> 6);
  const float ei = ha1g[row];
  const int* __restrict__ arow = adj + (size_t)row * N;
  u64* __restrict__ mrow = msk + (size_t)row * 128;
  float m = -3.0e38f, s = 0.f;
  for (int it = 0; it < 32; ++it) {
    const int j0 = it * 256 + lane * 4;
    const int4 a4 = *(const int4*)(arow + j0);
    const float4 h2 = *(const float4*)(ha2g + j0);
    const bool b0 = a4.x > 0, b1 = a4.y > 0, b2 = a4.z > 0, b3 = a4.w > 0;
    #define ONLINE(bb, vv) { \
      const float t0 = ei + (vv); \
      const float e = lrelu(t0); \
      const float mn = (bb) ? fmaxf(m, e) : m; \
      s = fmaf(s, __expf(m - mn), (bb) ? __expf(e - mn) : 0.f); \
      m = mn; }
    ONLINE(b0, h2.x) ONLINE(b1, h2.y) ONLINE(b2, h2.z) ONLINE(b3, h2.w)
    #undef ONLINE
    if (WM) {
      const u64 q0 = __ballot(b0), q1 = __ballot(b1);
      const u64 q2 = __ballot(b2), q3 = __ballot(b3);
      if (lane == 0) {
        u64x2 v01 = {q0, q1}, v23 = {q2, q3};
        *(u64x2*)(mrow + it * 4) = v01;
        *(u64x2*)(mrow + it * 4 + 2) = v23;
      }
    }
  }
  #pragma unroll
  for (int off = 32; off; off >>= 1) {
    const float mo = __shfl_xor(m, off);
    const float so = __shfl_xor(s, off);
    const float mn = fmaxf(m, mo);
    s = s * __expf(m - mn) + so * __expf(mo - mn);
    m = mn;
  }
  if (lane == 0) lse_row[row] = (s > 0.f) ? (m + __logf(s)) : 3.0e38f;
}

// Kernel C: barrier-free. 16 rows/block, 8 waves; wave w owns j-slice [w*1024,(w+1)*1024).
// Each lane computes p DIRECTLY in MFMA A-frag layout (row=l&15, k-chunk=(l>>4)*8):
// p once per (row,j) -> attn store (2x float4) + bf16 A-frag in regs; 8 independent MFMAs
// (one per 16-feature group, B-frag straight from L2-resident h_t). LDS atomic reduce at end.
template <int UA>
__global__ __launch_bounds__(512) void k_pv(
    const int* __restrict__ adj, const u64* __restrict__ msk,
    const unsigned short* __restrict__ h_t, const float* __restrict__ ha1g,
    const float* __restrict__ ha2g, const float* __restrict__ lse_row,
    float* __restrict__ h1, float* __restrict__ attn) {
  __shared__ float red[16][128];
  const int t = threadIdx.x;
  const int lane = t & 63;
  const int w = t >> 6;
  const int base = blockIdx.x * 16;
  const int r = lane & 15;          // A-frag row / B-frag col
  const int jc = lane >> 4;         // 0..3 k-chunk
  const int row = base + r;
  const float ei = ha1g[row];
  const float nls = lse_row[row];
  const u64* __restrict__ mrow = msk + (size_t)row * 128;
  const int* __restrict__ arow = adj + (size_t)row * N;
  float* __restrict__ atrow = attn + (size_t)row * N;
  const int jbase = w * 1024;

  f32x4 acc[8];
  #pragma unroll
  for (int f = 0; f < 8; ++f) acc[f] = (f32x4){0.f, 0.f, 0.f, 0.f};

  for (int jt = 0; jt < 32; ++jt) {
    const int j0 = jbase + jt * 32 + jc * 8;
    unsigned int bits8;
    if constexpr (UA) {
      const int4 a0 = *(const int4*)(arow + j0);
      const int4 a1 = *(const int4*)(arow + j0 + 4);
      bits8 = (a0.x > 0 ? 1u : 0u) | (a0.y > 0 ? 2u : 0u) | (a0.z > 0 ? 4u : 0u) |
              (a0.w > 0 ? 8u : 0u) | (a1.x > 0 ? 16u : 0u) | (a1.y > 0 ? 32u : 0u) |
              (a1.z > 0 ? 64u : 0u) | (a1.w > 0 ? 128u : 0u);
    } else {
      // Interleaved decode: bit for j0+d is word it*4+(d&3), position l+(d>>2); l even.
      const int it = j0 >> 8;
      const int l = (j0 >> 2) & 63;
      const u64x2 qa = *(const u64x2*)(mrow + it * 4);
      const u64x2 qb = *(const u64x2*)(mrow + it * 4 + 2);
      const unsigned int n0 = (unsigned int)((qa.x >> l) & 3ull);  // j0+0 (bit0), j0+4 (bit1)
      const unsigned int n1 = (unsigned int)((qa.y >> l) & 3ull);  // j0+1, j0+5
      const unsigned int n2 = (unsigned int)((qb.x >> l) & 3ull);  // j0+2, j0+6
      const unsigned int n3 = (unsigned int)((qb.y >> l) & 3ull);  // j0+3, j0+7
      bits8 = (n0 & 1u) | ((n1 & 1u) << 1) | ((n2 & 1u) << 2) | ((n3 & 1u) << 3) |
              ((n0 >> 1) << 4) | ((n1 >> 1) << 5) | ((n2 >> 1) << 6) | ((n3 >> 1) << 7);
    }
    const float4 hA = *(const float4*)(ha2g + j0);
    const float4 hB = *(const float4*)(ha2g + j0 + 4);
    float p[8];
    p[0] = (bits8 & 1u)   ? __expf(lrelu(ei + hA.x) - nls) : 0.f;
    p[1] = (bits8 & 2u)   ? __expf(lrelu(ei + hA.y) - nls) : 0.f;
    p[2] = (bits8 & 4u)   ? __expf(lrelu(ei + hA.z) - nls) : 0.f;
    p[3] = (bits8 & 8u)   ? __expf(lrelu(ei + hA.w) - nls) : 0.f;
    p[4] = (bits8 & 16u)  ? __expf(lrelu(ei + hB.x) - nls) : 0.f;
    p[5] = (bits8 & 32u)  ? __expf(lrelu(ei + hB.y) - nls) : 0.f;
    p[6] = (bits8 & 64u)  ? __expf(lrelu(ei + hB.z) - nls) : 0.f;
    p[7] = (bits8 & 128u) ? __expf(lrelu(ei + hB.w) - nls) : 0.f;
    *(float4*)(atrow + j0) = make_float4(p[0], p[1], p[2], p[3]);
    *(float4*)(atrow + j0 + 4) = make_float4(p[4], p[5], p[6], p[7]);
    union { bf16x8 v; unsigned short us[8]; } avu;
    avu.us[0] = f2bf(p[0]); avu.us[1] = f2bf(p[1]);
    avu.us[2] = f2bf(p[2]); avu.us[3] = f2bf(p[3]);
    avu.us[4] = f2bf(p[4]); avu.us[5] = f2bf(p[5]);
    avu.us[6] = f2bf(p[6]); avu.us[7] = f2bf(p[7]);
    const bf16x8 av = avu.v;
    #pragma unroll
    for (int f = 0; f < 8; ++f) {
      const bf16x8 bv = *(const bf16x8*)(h_t + (size_t)(f * 16 + r) * N + j0);
      acc[f] = __builtin_amdgcn_mfma_f32_16x16x32_bf16(av, bv, acc[f], 0, 0, 0);
    }
  }

  // Cross-wave reduce: D[row=jc*4+i][col=r] per f-group, summed over the 8 j-slices.
  *(float4*)&red[t >> 5][(t & 31) * 4] = make_float4(0.f, 0.f, 0.f, 0.f);
  __syncthreads();
  #pragma unroll
  for (int f = 0; f < 8; ++f) {
    #pragma unroll
    for (int i = 0; i < 4; ++i)
      atomicAdd(&red[jc * 4 + i][f * 16 + r], acc[f][i]);
  }
  __syncthreads();
  {
    const int orow = t >> 5;
    const int oc = (t & 31) * 4;
    float4 v = *(float4*)&red[orow][oc];
    v.x = v.x > 0.f ? v.x : __expf(v.x) - 1.f;
    v.y = v.y > 0.f ? v.y : __expf(v.y) - 1.f;
    v.z = v.z > 0.f ? v.z : __expf(v.z) - 1.f;
    v.w = v.w > 0.f ? v.w : __expf(v.w) - 1.f;
    *(float4*)(h1 + (size_t)(base + orow) * FO + oc) = v;
  }
}

extern "C" void kernel_launch(void* const* d_in, const int* in_sizes, int n_in,
                              void* d_out, int out_size, void* d_ws, size_t ws_size,
                              hipStream_t stream) {
  const float* x = (const float*)d_in[0];
  const int* adj = (const int*)d_in[1];
  const float* W = (const float*)d_in[2];
  const float* a = (const float*)d_in[3];
  float* h1 = (float*)d_out;
  float* attn = (float*)d_out + (size_t)N * FO;

  char* wsb = (char*)d_ws;
  unsigned short* h_t = (unsigned short*)wsb;                       // 2 MB
  float* ha1 = (float*)(wsb + (size_t)FO * N * 2);                  // 32 KB
  float* ha2 = ha1 + N;                                             // 32 KB
  float* lse = ha2 + N;                                             // 32 KB
  const size_t msk_off = (size_t)FO * N * 2 + 3 * (size_t)N * 4;    // 2,195,456
  u64* msk = (u64*)(wsb + msk_off);                                 // 8 MB
  const size_t need = msk_off + (size_t)N * 128 * 8;

  k_prep<<<N / 16, 256, 0, stream>>>(x, W, a, h_t, ha1, ha2);
  if (ws_size >= need) {
    k_mask<1><<<N / 4, 256, 0, stream>>>(adj, ha1, ha2, msk, lse);
    k_pv<0><<<N / 16, 512, 0, stream>>>(adj, msk, h_t, ha1, ha2, lse, h1, attn);
  } else {
    k_mask<0><<<N / 4, 256, 0, stream>>>(adj, ha1, ha2, msk, lse);
    k_pv<1><<<N / 16, 512, 0, stream>>>(adj, msk, h_t, ha1, ha2, lse, h1, attn);
  }
}

// Round 7
// 263.759 us; speedup vs baseline: 1.2812x; 1.2812x over previous
//
#include <hip/hip_runtime.h>

#define N 8192
#define FI 256
#define FO 128

typedef short bf16x8 __attribute__((ext_vector_type(8)));
typedef float f32x4 __attribute__((ext_vector_type(4)));
typedef unsigned long long u64;
typedef u64 u64x2 __attribute__((ext_vector_type(2)));

static __device__ __forceinline__ unsigned short f2bf(float x) {
  unsigned int u = __builtin_bit_cast(unsigned int, x);
  u = (u + 0x7fffu + ((u >> 16) & 1u)) >> 16;
  return (unsigned short)u;
}
static __device__ __forceinline__ float lrelu(float x) {
  return fmaxf(x, 0.01f * x);
}

// Kernel A: h = x@W (f32 accum); write h transposed bf16 h_t[FO][N]; ha1 = h@a1, ha2 = h@a2.
__global__ __launch_bounds__(256) void k_prep(
    const float* __restrict__ x, const float* __restrict__ W, const float* __restrict__ a,
    unsigned short* __restrict__ h_t, float* __restrict__ ha1, float* __restrict__ ha2) {
  __shared__ float xs[16][256];
  __shared__ float redA[16][2], redB[16][2];
  const int t = threadIdx.x;
  const int i0 = blockIdx.x * 16;
  #pragma unroll
  for (int ii = 0; ii < 16; ++ii)
    xs[ii][t & 255] = x[(long long)(i0 + ii) * FI + t];
  __syncthreads();
  const int rg = t >> 7;
  const int f = t & 127;
  float accs[8] = {0.f, 0.f, 0.f, 0.f, 0.f, 0.f, 0.f, 0.f};
  for (int k = 0; k < 256; ++k) {
    const float wv = W[k * FO + f];
    #pragma unroll
    for (int rr = 0; rr < 8; ++rr) accs[rr] = fmaf(xs[rg * 8 + rr][k], wv, accs[rr]);
  }
  {
    ushort4 s0, s1;
    s0.x = f2bf(accs[0]); s0.y = f2bf(accs[1]); s0.z = f2bf(accs[2]); s0.w = f2bf(accs[3]);
    s1.x = f2bf(accs[4]); s1.y = f2bf(accs[5]); s1.z = f2bf(accs[6]); s1.w = f2bf(accs[7]);
    unsigned short* dst = h_t + (long long)f * N + i0 + rg * 8;
    *(ushort4*)dst = s0;
    *(ushort4*)(dst + 4) = s1;
  }
  const float a1f = a[f];
  const float a2f = a[FO + f];
  const int lane = t & 63;
  const int wig = (t >> 6) & 1;
  #pragma unroll
  for (int rr = 0; rr < 8; ++rr) {
    float v1 = accs[rr] * a1f;
    float v2 = accs[rr] * a2f;
    #pragma unroll
    for (int off = 32; off; off >>= 1) { v1 += __shfl_xor(v1, off); v2 += __shfl_xor(v2, off); }
    if (lane == 0) { redA[rg * 8 + rr][wig] = v1; redB[rg * 8 + rr][wig] = v2; }
  }
  __syncthreads();
  if (t < 16) {
    ha1[i0 + t] = redA[t][0] + redA[t][1];
    ha2[i0 + t] = redB[t][0] + redB[t][1];
  }
}

// Kernel B: one wave per row, TWO-PHASE, no LDS stage (lrelu monotone =>
// m = lrelu(ei + max_masked ha2)). Phase 1: stream adj once -> bit regs + ballot masks
// (ws) + masked max via 4 independent accumulators (no exp in serial chain).
// Phase 2: independent exps (ha2 re-read, L2-hot) -> s. Writes lse = m + log(s).
// Mask layout (ballot-interleaved): bit l of word mrow[it*4 + k] <-> j = it*256 + 4*l + k.
template <int WM>
__global__ __launch_bounds__(256) void k_mask(
    const int* __restrict__ adj, const float* __restrict__ ha1g, const float* __restrict__ ha2g,
    u64* __restrict__ msk, float* __restrict__ lse_row) {
  const int t = threadIdx.x;
  const int lane = t & 63;
  const int row = blockIdx.x * 4 + (t >> 6);
  const float ei = ha1g[row];
  const int* __restrict__ arow = adj + (size_t)row * N;
  u64* __restrict__ mrow = msk + (size_t)row * 128;
  unsigned int bits0 = 0, bits1 = 0, bits2 = 0, bits3 = 0;
  float m0 = -3.0e38f, m1 = -3.0e38f, m2 = -3.0e38f, m3 = -3.0e38f;
  for (int it = 0; it < 32; ++it) {
    const int j0 = it * 256 + lane * 4;
    const int4 a4 = *(const int4*)(arow + j0);
    const float4 h2 = *(const float4*)(ha2g + j0);
    const bool b0 = a4.x > 0, b1 = a4.y > 0, b2 = a4.z > 0, b3 = a4.w > 0;
    bits0 |= (b0 ? 1u : 0u) << it;
    bits1 |= (b1 ? 1u : 0u) << it;
    bits2 |= (b2 ? 1u : 0u) << it;
    bits3 |= (b3 ? 1u : 0u) << it;
    m0 = fmaxf(m0, b0 ? h2.x : -3.0e38f);
    m1 = fmaxf(m1, b1 ? h2.y : -3.0e38f);
    m2 = fmaxf(m2, b2 ? h2.z : -3.0e38f);
    m3 = fmaxf(m3, b3 ? h2.w : -3.0e38f);
    if (WM) {
      const u64 q0 = __ballot(b0), q1 = __ballot(b1);
      const u64 q2 = __ballot(b2), q3 = __ballot(b3);
      if (lane == 0) {
        u64x2 v01 = {q0, q1}, v23 = {q2, q3};
        *(u64x2*)(mrow + it * 4) = v01;
        *(u64x2*)(mrow + it * 4 + 2) = v23;
      }
    }
  }
  float mloc = fmaxf(fmaxf(m0, m1), fmaxf(m2, m3));
  #pragma unroll
  for (int off = 32; off; off >>= 1) mloc = fmaxf(mloc, __shfl_xor(mloc, off));
  const float m = lrelu(ei + mloc);
  float s0 = 0.f, s1 = 0.f, s2 = 0.f, s3 = 0.f;
  for (int it = 0; it < 32; ++it) {
    const int j0 = it * 256 + lane * 4;
    const float4 h2 = *(const float4*)(ha2g + j0);
    s0 += ((bits0 >> it) & 1) ? __expf(lrelu(ei + h2.x) - m) : 0.f;
    s1 += ((bits1 >> it) & 1) ? __expf(lrelu(ei + h2.y) - m) : 0.f;
    s2 += ((bits2 >> it) & 1) ? __expf(lrelu(ei + h2.z) - m) : 0.f;
    s3 += ((bits3 >> it) & 1) ? __expf(lrelu(ei + h2.w) - m) : 0.f;
  }
  float s = (s0 + s1) + (s2 + s3);
  #pragma unroll
  for (int off = 32; off; off >>= 1) s += __shfl_xor(s, off);
  if (lane == 0) lse_row[row] = (s > 0.f) ? (m + __logf(s)) : 3.0e38f;
}

// Kernel C: 16 rows/block, FOUR waves (256 thr) -> ~5 blocks/CU = 5 independent barrier
// groups overlapping each other's stalls. Per 128-j tile: p-phase (each thread 8 j of one
// row: mask decode + exp + nontemporal attn store + bf16 p -> double-buffered LDS);
// PV-phase: wave owns 32 features (2 f-groups), A-frag ds_read, B-frag register-prefetched
// straight from L2-resident h_t. One barrier per iter.
template <int UA>
__global__ __launch_bounds__(256, 4) void k_pv(
    const int* __restrict__ adj, const u64* __restrict__ msk,
    const unsigned short* __restrict__ h_t, const float* __restrict__ ha1g,
    const float* __restrict__ ha2g, const float* __restrict__ lse_row,
    float* __restrict__ h1, float* __restrict__ attn) {
  __shared__ unsigned short p_lds[2][16][136];
  const int t = threadIdx.x;
  const int lane = t & 63;
  const int w = t >> 6;            // wave 0..3
  const int base = blockIdx.x * 16;
  const int pr = t >> 4;           // p-phase row 0..15
  const int pjw = t & 15;          // 8 consecutive j per thread
  const float ei = ha1g[base + pr];
  const float nls = lse_row[base + pr];
  const u64* __restrict__ mrow = msk + (size_t)(base + pr) * 128;
  const int* __restrict__ arow = adj + (size_t)(base + pr) * N;
  float* __restrict__ atrow = attn + (size_t)(base + pr) * N;

  const int f0 = w * 32;           // wave's 32 output features (2 groups of 16)
  const unsigned short* __restrict__ hb0 =
      h_t + (size_t)(f0 + (lane & 15)) * N + (lane >> 4) * 8;
  const unsigned short* __restrict__ hb1 = hb0 + (size_t)16 * N;
  const unsigned short* pfrag0 = &p_lds[0][lane & 15][(lane >> 4) * 8];

  f32x4 acc0 = {0.f, 0.f, 0.f, 0.f};
  f32x4 acc1 = {0.f, 0.f, 0.f, 0.f};

  auto compute_p = [&](int jt) {
    const int j0 = jt * 128 + pjw * 8;
    unsigned int bits8;
    if constexpr (UA) {
      const int4 a0 = *(const int4*)(arow + j0);
      const int4 a1 = *(const int4*)(arow + j0 + 4);
      bits8 = (a0.x > 0 ? 1u : 0u) | (a0.y > 0 ? 2u : 0u) | (a0.z > 0 ? 4u : 0u) |
              (a0.w > 0 ? 8u : 0u) | (a1.x > 0 ? 16u : 0u) | (a1.y > 0 ? 32u : 0u) |
              (a1.z > 0 ? 64u : 0u) | (a1.w > 0 ? 128u : 0u);
    } else {
      // Interleaved decode: bit for j0+d is word it*4+(d&3), position l+(d>>2); l even.
      const int it = j0 >> 8;
      const int l = (j0 >> 2) & 63;
      const u64x2 qa = *(const u64x2*)(mrow + it * 4);
      const u64x2 qb = *(const u64x2*)(mrow + it * 4 + 2);
      const unsigned int n0 = (unsigned int)((qa.x >> l) & 3ull);
      const unsigned int n1 = (unsigned int)((qa.y >> l) & 3ull);
      const unsigned int n2 = (unsigned int)((qb.x >> l) & 3ull);
      const unsigned int n3 = (unsigned int)((qb.y >> l) & 3ull);
      bits8 = (n0 & 1u) | ((n1 & 1u) << 1) | ((n2 & 1u) << 2) | ((n3 & 1u) << 3) |
              ((n0 >> 1) << 4) | ((n1 >> 1) << 5) | ((n2 >> 1) << 6) | ((n3 >> 1) << 7);
    }
    const float4 hA = *(const float4*)(ha2g + j0);
    const float4 hB = *(const float4*)(ha2g + j0 + 4);
    float p[8];
    p[0] = (bits8 & 1u)   ? __expf(lrelu(ei + hA.x) - nls) : 0.f;
    p[1] = (bits8 & 2u)   ? __expf(lrelu(ei + hA.y) - nls) : 0.f;
    p[2] = (bits8 & 4u)   ? __expf(lrelu(ei + hA.z) - nls) : 0.f;
    p[3] = (bits8 & 8u)   ? __expf(lrelu(ei + hA.w) - nls) : 0.f;
    p[4] = (bits8 & 16u)  ? __expf(lrelu(ei + hB.x) - nls) : 0.f;
    p[5] = (bits8 & 32u)  ? __expf(lrelu(ei + hB.y) - nls) : 0.f;
    p[6] = (bits8 & 64u)  ? __expf(lrelu(ei + hB.z) - nls) : 0.f;
    p[7] = (bits8 & 128u) ? __expf(lrelu(ei + hB.w) - nls) : 0.f;
    f32x4 pv0 = {p[0], p[1], p[2], p[3]};
    f32x4 pv1 = {p[4], p[5], p[6], p[7]};
    __builtin_nontemporal_store(pv0, (f32x4*)(atrow + j0));
    __builtin_nontemporal_store(pv1, (f32x4*)(atrow + j0 + 4));
    ushort4 pb0, pb1;
    pb0.x = f2bf(p[0]); pb0.y = f2bf(p[1]); pb0.z = f2bf(p[2]); pb0.w = f2bf(p[3]);
    pb1.x = f2bf(p[4]); pb1.y = f2bf(p[5]); pb1.z = f2bf(p[6]); pb1.w = f2bf(p[7]);
    *(ushort4*)&p_lds[(jt & 1)][pr][pjw * 8] = pb0;
    *(ushort4*)&p_lds[(jt & 1)][pr][pjw * 8 + 4] = pb1;
  };

  bf16x8 hC0[4], hC1[4], hN0[4], hN1[4];
  compute_p(0);
  #pragma unroll
  for (int ks = 0; ks < 4; ++ks) {
    hC0[ks] = *(const bf16x8*)(hb0 + ks * 32);
    hC1[ks] = *(const bf16x8*)(hb1 + ks * 32);
  }
  __syncthreads();

  for (int jt = 0; jt < 64; ++jt) {
    if (jt < 63) {
      compute_p(jt + 1);
      #pragma unroll
      for (int ks = 0; ks < 4; ++ks) {
        hN0[ks] = *(const bf16x8*)(hb0 + (jt + 1) * 128 + ks * 32);
        hN1[ks] = *(const bf16x8*)(hb1 + (jt + 1) * 128 + ks * 32);
      }
    }
    const unsigned short* pf = pfrag0 + (jt & 1) * (16 * 136);
    #pragma unroll
    for (int ks = 0; ks < 4; ++ks) {
      const bf16x8 av = *(const bf16x8*)(pf + ks * 32);
      acc0 = __builtin_amdgcn_mfma_f32_16x16x32_bf16(av, hC0[ks], acc0, 0, 0, 0);
      acc1 = __builtin_amdgcn_mfma_f32_16x16x32_bf16(av, hC1[ks], acc1, 0, 0, 0);
    }
    if (jt < 63) {
      __syncthreads();
      #pragma unroll
      for (int ks = 0; ks < 4; ++ks) { hC0[ks] = hN0[ks]; hC1[ks] = hN1[ks]; }
    }
  }
  { // epilogue: D[row=(l>>4)*4+reg][col=l&15] per f-group, elu
    const int rbase = (lane >> 4) * 4;
    const int col = lane & 15;
    #pragma unroll
    for (int rgi = 0; rgi < 4; ++rgi) {
      float v = acc0[rgi];
      v = v > 0.f ? v : __expf(v) - 1.f;
      h1[(long long)(base + rbase + rgi) * FO + f0 + col] = v;
      float u = acc1[rgi];
      u = u > 0.f ? u : __expf(u) - 1.f;
      h1[(long long)(base + rbase + rgi) * FO + f0 + 16 + col] = u;
    }
  }
}

extern "C" void kernel_launch(void* const* d_in, const int* in_sizes, int n_in,
                              void* d_out, int out_size, void* d_ws, size_t ws_size,
                              hipStream_t stream) {
  const float* x = (const float*)d_in[0];
  const int* adj = (const int*)d_in[1];
  const float* W = (const float*)d_in[2];
  const float* a = (const float*)d_in[3];
  float* h1 = (float*)d_out;
  float* attn = (float*)d_out + (size_t)N * FO;

  char* wsb = (char*)d_ws;
  unsigned short* h_t = (unsigned short*)wsb;                       // 2 MB
  float* ha1 = (float*)(wsb + (size_t)FO * N * 2);                  // 32 KB
  float* ha2 = ha1 + N;                                             // 32 KB
  float* lse = ha2 + N;                                             // 32 KB
  const size_t msk_off = (size_t)FO * N * 2 + 3 * (size_t)N * 4;    // 2,195,456
  u64* msk = (u64*)(wsb + msk_off);                                 // 8 MB
  const size_t need = msk_off + (size_t)N * 128 * 8;

  k_prep<<<N / 16, 256, 0, stream>>>(x, W, a, h_t, ha1, ha2);
  if (ws_size >= need) {
    k_mask<1><<<N / 4, 256, 0, stream>>>(adj, ha1, ha2, msk, lse);
    k_pv<0><<<N / 16, 256, 0, stream>>>(adj, msk, h_t, ha1, ha2, lse, h1, attn);
  } else {
    k_mask<0><<<N / 4, 256, 0, stream>>>(adj, ha1, ha2, msk, lse);
    k_pv<1><<<N / 16, 256, 0, stream>>>(adj, msk, h_t, ha1, ha2, lse, h1, attn);
  }
}